// Round 3
// baseline (18735.428 us; speedup 1.0000x reference)
//
#include <hip/hip_runtime.h>

#define DI __device__ __forceinline__

typedef __attribute__((ext_vector_type(4))) float  f32x4;
typedef __attribute__((ext_vector_type(8))) short  s16x8;
typedef __attribute__((ext_vector_type(8))) __bf16 bf16x8;

// ---------------- constants ----------------
constexpr int S_   = 256;
constexpr int B_   = 512;
constexpr int H_   = 512;
constexpr int KP_  = 320;   // padded 300
constexpr int ALD_ = 832;   // act row: [xt 0..320 | htm 320..832]
constexpr int NRING = 34;
constexpr int NWG  = 256;   // persistent workgroups (== CU count)
constexpr size_t HSLOT = 512 * 512;  // elements per hs slot

// ---------------- workspace layout (bytes) ----------------
constexpr size_t OFF_XIN = 0;                              // bf16 [S][B][320]
constexpr size_t SZ_XIN  = (size_t)S_ * B_ * KP_ * 2;
constexpr size_t OFF_U   = OFF_XIN + SZ_XIN;               // f32 [B][S][64]
constexpr size_t SZ_U    = (size_t)B_ * S_ * 64 * 4;
constexpr size_t OFF_HS  = OFF_U + SZ_U;                   // bf16 ring [34][512][512]
constexpr size_t SZ_HS   = (size_t)NRING * HSLOT * 2;
constexpr size_t OFF_ACT = OFF_HS + SZ_HS;                 // bf16 [512][832]
constexpr size_t SZ_ACT  = (size_t)B_ * ALD_ * 2;
constexpr size_t OFF_HFP = OFF_ACT + SZ_ACT;               // f32 [512][512]
constexpr size_t SZ_HFP  = (size_t)B_ * H_ * 4;
constexpr size_t OFF_WPT = OFF_HFP + SZ_HFP;               // bf16 [320][320]
constexpr size_t SZ_WPT  = (size_t)320 * 320 * 2;
constexpr size_t OFF_QPT = OFF_WPT + SZ_WPT;               // bf16 [320][512]
constexpr size_t SZ_QPT  = (size_t)320 * 512 * 2;
constexpr size_t OFF_RPT = OFF_QPT + SZ_QPT;               // bf16 [512][320]
constexpr size_t SZ_RPT  = (size_t)512 * 320 * 2;
constexpr size_t OFF_WGT = OFF_RPT + SZ_RPT;               // bf16 [2048][832]
constexpr size_t SZ_WGT  = (size_t)2048 * 832 * 2;
constexpr size_t OFF_BG  = OFF_WGT + SZ_WGT;               // f32 [2048]
constexpr size_t SZ_BG   = 2048 * 4;
constexpr size_t OFF_VT  = OFF_BG + SZ_BG;                 // bf16 [64][512]
constexpr size_t SZ_VT   = (size_t)64 * 512 * 2;
constexpr size_t OFF_BAR = OFF_VT + SZ_VT;                 // u32 barrier counters
constexpr size_t SZ_BAR  = 4096;
constexpr size_t WS_NEED = OFF_BAR + SZ_BAR;               // ~141.7 MB

// ---------------- helpers ----------------
DI unsigned short f2bf(float x) {
  unsigned int u = __float_as_uint(x);
  unsigned int r = (u + 0x7FFFu + ((u >> 16) & 1u)) >> 16;
  return (unsigned short)r;
}
DI float bf2f(unsigned short h) { return __uint_as_float(((unsigned int)h) << 16); }

DI float sigm(float x) {
  float e = __builtin_amdgcn_exp2f(x * -1.44269504088896f);
  return __builtin_amdgcn_rcpf(1.0f + e);
}
DI float tanh_(float x) {
  x = fminf(fmaxf(x, -15.0f), 15.0f);
  float e = __builtin_amdgcn_exp2f(x * 2.88539008177793f);
  return (e - 1.0f) * __builtin_amdgcn_rcpf(e + 1.0f);
}
DI bf16x8 asbf(s16x8 v) { return __builtin_bit_cast(bf16x8, v); }

// ---------------- 64x64 bf16 GEMM core ----------------
// A: row-major [M][lda] bf16 (tile rows m0..m0+64). B: row-major B^T [N][ldb] bf16
// (tile rows n0..n0+64): B^T[n][k] = B[k][n]. K = NK*32. 256 threads, 4 waves 2x2,
// wave tile 32x32 (2x2 16x16x32 frags). LDS double-buffered, reg-staged.
template<int NK>
DI void gemm_bf16(const unsigned short* Ab, int lda,
                  const unsigned short* Bb, int ldb,
                  short* sA, short* sB, f32x4 acc[2][2])
{
  const int tid  = threadIdx.x;
  const int lane = tid & 63;
  const int w = tid >> 6, wm = w >> 1, wn = w & 1;
  const unsigned short* ga = Ab + (tid >> 2) * lda + (tid & 3) * 8;
  const unsigned short* gb = Bb + (tid >> 2) * ldb + (tid & 3) * 8;
  const int arow0 = (wm * 32 + (lane & 15)) * 32 + (lane >> 4) * 8;
  const int brow0 = (wn * 32 + (lane & 15)) * 32 + (lane >> 4) * 8;

  s16x8 va = *(const s16x8*)ga;
  s16x8 vb = *(const s16x8*)gb;
  *(s16x8*)&sA[tid * 8] = va;
  *(s16x8*)&sB[tid * 8] = vb;
  __syncthreads();
  for (int k = 0; k < NK; ++k) {
    const int cur = (k & 1) * 2048;
    if (k + 1 < NK) {
      va = *(const s16x8*)(ga + (k + 1) * 32);
      vb = *(const s16x8*)(gb + (k + 1) * 32);
    }
    s16x8 a0 = *(const s16x8*)&sA[cur + arow0];
    s16x8 a1 = *(const s16x8*)&sA[cur + arow0 + 16 * 32];
    s16x8 b0 = *(const s16x8*)&sB[cur + brow0];
    s16x8 b1 = *(const s16x8*)&sB[cur + brow0 + 16 * 32];
    acc[0][0] = __builtin_amdgcn_mfma_f32_16x16x32_bf16(asbf(a0), asbf(b0), acc[0][0], 0, 0, 0);
    acc[0][1] = __builtin_amdgcn_mfma_f32_16x16x32_bf16(asbf(a0), asbf(b1), acc[0][1], 0, 0, 0);
    acc[1][0] = __builtin_amdgcn_mfma_f32_16x16x32_bf16(asbf(a1), asbf(b0), acc[1][0], 0, 0, 0);
    acc[1][1] = __builtin_amdgcn_mfma_f32_16x16x32_bf16(asbf(a1), asbf(b1), acc[1][1], 0, 0, 0);
    if (k + 1 < NK) {
      const int nxt = ((k + 1) & 1) * 2048;
      *(s16x8*)&sA[nxt + tid * 8] = va;
      *(s16x8*)&sB[nxt + tid * 8] = vb;
    }
    __syncthreads();
  }
}

// Variant: A is fp32 with real K = KREAL (<= NK*32), converted to bf16 while staging.
template<int NK, int KREAL>
DI void gemm_f32A(const float* Af, int lda,
                  const unsigned short* Bb, int ldb,
                  short* sA, short* sB, f32x4 acc[2][2])
{
  const int tid  = threadIdx.x;
  const int lane = tid & 63;
  const int w = tid >> 6, wm = w >> 1, wn = w & 1;
  const float* ga = Af + (tid >> 2) * lda;
  const int cseg  = (tid & 3) * 8;
  const unsigned short* gb = Bb + (tid >> 2) * ldb + (tid & 3) * 8;
  const int arow0 = (wm * 32 + (lane & 15)) * 32 + (lane >> 4) * 8;
  const int brow0 = (wn * 32 + (lane & 15)) * 32 + (lane >> 4) * 8;

  auto loadA = [&](int k) -> s16x8 {
    s16x8 r;
    const int c0 = k * 32 + cseg;
    if (c0 + 8 <= KREAL) {
      float4 f0 = *(const float4*)(ga + c0);
      float4 f1 = *(const float4*)(ga + c0 + 4);
      r[0] = (short)f2bf(f0.x); r[1] = (short)f2bf(f0.y);
      r[2] = (short)f2bf(f0.z); r[3] = (short)f2bf(f0.w);
      r[4] = (short)f2bf(f1.x); r[5] = (short)f2bf(f1.y);
      r[6] = (short)f2bf(f1.z); r[7] = (short)f2bf(f1.w);
    } else {
      #pragma unroll
      for (int j = 0; j < 8; ++j) {
        float x = (c0 + j < KREAL) ? ga[c0 + j] : 0.0f;
        r[j] = (short)f2bf(x);
      }
    }
    return r;
  };

  s16x8 va = loadA(0);
  s16x8 vb = *(const s16x8*)gb;
  *(s16x8*)&sA[tid * 8] = va;
  *(s16x8*)&sB[tid * 8] = vb;
  __syncthreads();
  for (int k = 0; k < NK; ++k) {
    const int cur = (k & 1) * 2048;
    if (k + 1 < NK) {
      va = loadA(k + 1);
      vb = *(const s16x8*)(gb + (k + 1) * 32);
    }
    s16x8 a0 = *(const s16x8*)&sA[cur + arow0];
    s16x8 a1 = *(const s16x8*)&sA[cur + arow0 + 16 * 32];
    s16x8 b0 = *(const s16x8*)&sB[cur + brow0];
    s16x8 b1 = *(const s16x8*)&sB[cur + brow0 + 16 * 32];
    acc[0][0] = __builtin_amdgcn_mfma_f32_16x16x32_bf16(asbf(a0), asbf(b0), acc[0][0], 0, 0, 0);
    acc[0][1] = __builtin_amdgcn_mfma_f32_16x16x32_bf16(asbf(a0), asbf(b1), acc[0][1], 0, 0, 0);
    acc[1][0] = __builtin_amdgcn_mfma_f32_16x16x32_bf16(asbf(a1), asbf(b0), acc[1][0], 0, 0, 0);
    acc[1][1] = __builtin_amdgcn_mfma_f32_16x16x32_bf16(asbf(a1), asbf(b1), acc[1][1], 0, 0, 0);
    if (k + 1 < NK) {
      const int nxt = ((k + 1) & 1) * 2048;
      *(s16x8*)&sA[nxt + tid * 8] = va;
      *(s16x8*)&sB[nxt + tid * 8] = vb;
    }
    __syncthreads();
  }
}

// epilogue iterator: f(rowl, coll, acc_value) for the 64x64 block tile
template<typename F>
DI void epiloop(f32x4 acc[2][2], F&& f) {
  const int lane = threadIdx.x & 63;
  const int w = threadIdx.x >> 6, wm = w >> 1, wn = w & 1;
  #pragma unroll
  for (int mi = 0; mi < 2; ++mi)
    #pragma unroll
    for (int ni = 0; ni < 2; ++ni)
      #pragma unroll
      for (int r = 0; r < 4; ++r) {
        const int rowl = wm * 32 + mi * 16 + (lane >> 4) * 4 + r;
        const int coll = wn * 32 + ni * 16 + (lane & 15);
        f(rowl, coll, acc[mi][ni][r]);
      }
}

// ---------------- prep kernels ----------------
__global__ void k_prep_wpt(const float* __restrict__ Wi, unsigned short* __restrict__ WpT) {
  int i = blockIdx.x * 256 + threadIdx.x;
  if (i >= 320 * 320) return;
  int n = i / 320, k = i % 320;
  float v = (n < 300 && k < 300) ? Wi[k * 300 + n] : 0.0f;
  WpT[i] = f2bf(v);
}
__global__ void k_prep_qpt(const float* __restrict__ Q, unsigned short* __restrict__ QpT) {
  int i = blockIdx.x * 256 + threadIdx.x;
  if (i >= 320 * 512) return;
  int n = i >> 9, k = i & 511;
  float v = (n < 300) ? Q[k * 300 + n] : 0.0f;
  QpT[i] = f2bf(v);
}
__global__ void k_prep_rpt(const float* __restrict__ R, unsigned short* __restrict__ RpT) {
  int i = blockIdx.x * 256 + threadIdx.x;
  if (i >= 512 * 320) return;
  int n = i / 320, k = i % 320;
  float v = (k < 300) ? R[k * 512 + n] : 0.0f;
  RpT[i] = f2bf(v);
}
__global__ void k_prep_wgt(const float* __restrict__ Wih, const float* __restrict__ Whh,
                           unsigned short* __restrict__ WgT) {
  int i = blockIdx.x * 256 + threadIdx.x;
  if (i >= 2048 * 832) return;
  int np = i / 832, k = i % 832;
  int c = np >> 2, g = np & 3, col = g * 512 + c;
  float v = 0.0f;
  if (k < 300) v = Wih[k * 2048 + col];
  else if (k >= 320) v = Whh[(k - 320) * 2048 + col];
  WgT[i] = f2bf(v);
}
__global__ void k_prep_bg(const float* __restrict__ bih, const float* __restrict__ bhh,
                          float* __restrict__ bg) {
  int i = blockIdx.x * 256 + threadIdx.x;
  if (i >= 2048) return;
  int c = i >> 2, g = i & 3, col = g * 512 + c;
  bg[i] = bih[col] + bhh[col];
}
__global__ void k_prep_vt(const float* __restrict__ Wc3, const float* __restrict__ Wc4,
                          const float* __restrict__ Wc5, unsigned short* __restrict__ VT) {
  int i = blockIdx.x * 256 + threadIdx.x;
  if (i >= 64 * 512) return;
  int j = i >> 9, k = i & 511;
  float v = 0.0f;
  if (j < 9)       { int f = j / 3,  dt = j % 3;        v = Wc3[(f * 3 + dt) * 512 + k]; }
  else if (j < 21) { int jj = j - 9;  int f = jj / 4, dt = jj % 4; v = Wc4[(f * 4 + dt) * 512 + k]; }
  else if (j < 36) { int jj = j - 21; int f = jj / 5, dt = jj % 5; v = Wc5[(f * 5 + dt) * 512 + k]; }
  VT[i] = f2bf(v);
}
__global__ void k_wsfail(float* out, int n, float v) {
  int i = blockIdx.x * 256 + threadIdx.x;
  if (i < n) out[i] = -v;
}

// ---------------- input projection ----------------
__global__ __launch_bounds__(256) void k_proj(const float* __restrict__ x,
                                              const unsigned short* __restrict__ WpT,
                                              const float* __restrict__ b_in,
                                              unsigned short* __restrict__ xin) {
  __shared__ short sA[4096], sB[4096];
  const int m0 = blockIdx.x * 64, n0 = blockIdx.y * 64;
  f32x4 acc[2][2];
  const f32x4 z = {0.f, 0.f, 0.f, 0.f};
  acc[0][0] = z; acc[0][1] = z; acc[1][0] = z; acc[1][1] = z;
  gemm_f32A<10, 300>(x + (size_t)m0 * 300, 300, WpT + n0 * 320, 320, sA, sB, acc);
  epiloop(acc, [&](int rowl, int coll, float vacc) {
    const int row = m0 + rowl, col = n0 + coll;
    float o = 0.0f;
    if (col < 300) o = tanh_(vacc + b_in[col]);
    const int b = row >> 8, s = row & 255;
    xin[(size_t)(s * 512 + b) * KP_ + col] = f2bf(o);
  });
}

// ---------------- persistent scan kernel ----------------
// 256 WGs x 256 threads, 1/CU. Loops all 256 timesteps with device-scope
// two-level grid barriers. Phases: P1 mog1 (40 WGs), P2 mog2 (64 WGs),
// P3 gates+cell (256 WGs, cell state in registers), convU every 32 steps.
__global__ __launch_bounds__(256) void k_scan(
    const unsigned short* __restrict__ xin,
    const unsigned short* __restrict__ QpT,
    const unsigned short* __restrict__ RpT,
    const unsigned short* __restrict__ WgT,
    const float* __restrict__ bg,
    const unsigned short* __restrict__ VT,
    unsigned short* __restrict__ hs,
    unsigned short* __restrict__ act,
    float* __restrict__ hfp,
    float* __restrict__ U,
    unsigned int* __restrict__ bar)
{
  __shared__ short sA[4096], sB[4096];
  __shared__ float gbuf[4096];
  const int wg  = blockIdx.x;
  const int tid = threadIdx.x;
  const f32x4 z = {0.f, 0.f, 0.f, 0.f};

  // gates tile assignment (static across all steps -> cell state in regs)
  const int gm0 = (wg >> 5) * 64;       // batch-row tile
  const int gn0 = (wg & 31) * 64;       // gate-col tile (permuted n' = 4c+g)
  float c_state[4] = {0.f, 0.f, 0.f, 0.f};

  int ep = 0;  // barrier epoch
  auto bar_sync = [&]() {
    __syncthreads();
    if (tid == 0) {
      const int g = wg >> 4;  // 16 groups of 16
      unsigned old = __hip_atomic_fetch_add(&bar[g * 32], 1u, __ATOMIC_ACQ_REL,
                                            __HIP_MEMORY_SCOPE_AGENT);
      if (old == (unsigned)ep * 16u + 15u)
        __hip_atomic_fetch_add(&bar[16 * 32], 1u, __ATOMIC_RELEASE,
                               __HIP_MEMORY_SCOPE_AGENT);
      const unsigned tgt = (unsigned)(ep + 1) * 16u;
      while (__hip_atomic_load(&bar[16 * 32], __ATOMIC_RELAXED,
                               __HIP_MEMORY_SCOPE_AGENT) < tgt)
        __builtin_amdgcn_s_sleep(2);
    }
    __syncthreads();
    __builtin_amdgcn_fence(__ATOMIC_ACQUIRE, "agent");
    ++ep;
  };

  for (int t = 0; t < S_; ++t) {
    const unsigned short* hst = hs + (size_t)(t % NRING) * HSLOT;
    unsigned short*       hso = hs + (size_t)((t + 1) % NRING) * HSLOT;

    // ---- P1: act[:,0:320] = 2*sigm(h_{t-1} @ Q) * xin_t  (40 tiles)
    if (wg < 40) {
      const int m0 = (wg / 5) * 64, n0 = (wg % 5) * 64;
      f32x4 acc[2][2];
      acc[0][0] = z; acc[0][1] = z; acc[1][0] = z; acc[1][1] = z;
      gemm_bf16<16>(hst + m0 * 512, 512, QpT + n0 * 512, 512, sA, sB, acc);
      const unsigned short* xin_t = xin + (size_t)t * 512 * KP_;
      epiloop(acc, [&](int rowl, int coll, float vacc) {
        const int row = m0 + rowl, col = n0 + coll;
        act[row * ALD_ + col] = f2bf(2.0f * sigm(vacc) * bf2f(xin_t[row * KP_ + col]));
      });
    }
    bar_sync();

    // ---- P2: act[:,320:832] = 2*sigm(xt @ R) * h_fp32  (64 tiles)
    if (wg < 64) {
      const int m0 = (wg >> 3) * 64, n0 = (wg & 7) * 64;
      f32x4 acc[2][2];
      acc[0][0] = z; acc[0][1] = z; acc[1][0] = z; acc[1][1] = z;
      gemm_bf16<10>(act + m0 * ALD_, ALD_, RpT + n0 * KP_, KP_, sA, sB, acc);
      epiloop(acc, [&](int rowl, int coll, float vacc) {
        const int row = m0 + rowl, col = n0 + coll;
        act[row * ALD_ + 320 + col] = f2bf(2.0f * sigm(vacc) * hfp[row * 512 + col]);
      });
    }
    bar_sync();

    // ---- P3: gates GEMM + cell update (256 tiles, Ct in registers)
    {
      f32x4 acc[2][2];
      acc[0][0] = z; acc[0][1] = z; acc[1][0] = z; acc[1][1] = z;
      gemm_bf16<26>(act + gm0 * ALD_, ALD_, WgT + gn0 * 832, 832, sA, sB, acc);
      epiloop(acc, [&](int rowl, int coll, float vacc) {
        gbuf[rowl * 64 + coll] = vacc;
      });
      __syncthreads();
      #pragma unroll
      for (int q = 0; q < 4; ++q) {
        const int item = q * 256 + tid;
        const int row = item >> 4, cu = item & 15;
        const float4 bb = *(const float4*)&bg[gn0 + cu * 4];
        const float iv = gbuf[row * 64 + cu * 4 + 0] + bb.x;
        const float fv = gbuf[row * 64 + cu * 4 + 1] + bb.y;
        const float gv = gbuf[row * 64 + cu * 4 + 2] + bb.z;
        const float ov = gbuf[row * 64 + cu * 4 + 3] + bb.w;
        const float cn = sigm(fv) * c_state[q] + sigm(iv) * tanh_(gv);
        const float h  = sigm(ov) * tanh_(cn);
        c_state[q] = cn;
        const int grow = gm0 + row, hcol = (gn0 >> 2) + cu;
        hfp[grow * 512 + hcol] = h;
        hso[grow * 512 + hcol] = f2bf(h);
      }
      __syncthreads();
    }
    bar_sync();

    // ---- convU every 32 steps (no extra barrier: 33-step ring slack)
    if ((t & 31) == 31) {
      const int c = t >> 5;
      const int m0c = wg * 64;
      const int tglob = 32 * c + (m0c >> 9);
      const int slot = (tglob + 1) % NRING;
      const int brow = m0c & 511;
      f32x4 acc[2][2];
      acc[0][0] = z; acc[0][1] = z; acc[1][0] = z; acc[1][1] = z;
      gemm_bf16<16>(hs + (size_t)slot * HSLOT + (size_t)brow * 512, 512, VT, 512, sA, sB, acc);
      epiloop(acc, [&](int rowl, int coll, float vacc) {
        U[((size_t)(brow + rowl) * 256 + tglob) * 64 + coll] = vacc;
      });
    }
  }
}

// window-sum + relu + global max pool + final linear
__global__ __launch_bounds__(256) void k_combine(const float* __restrict__ U,
                                                 const float* __restrict__ bc3,
                                                 const float* __restrict__ bc4,
                                                 const float* __restrict__ bc5,
                                                 const float* __restrict__ Wl,
                                                 const float* __restrict__ bl,
                                                 float* __restrict__ out) {
  const int b = blockIdx.x;
  const int p = threadIdx.x;
  const float* Ub = U + (size_t)b * (256 * 64);
  float v[9];
  #pragma unroll
  for (int j = 0; j < 9; ++j) v[j] = -1e30f;
  if (p < 254) {
    #pragma unroll
    for (int f = 0; f < 3; ++f)
      v[f] = Ub[(p + 0) * 64 + f * 3 + 0] + Ub[(p + 1) * 64 + f * 3 + 1] + Ub[(p + 2) * 64 + f * 3 + 2];
  }
  if (p < 253) {
    #pragma unroll
    for (int f = 0; f < 3; ++f)
      v[3 + f] = Ub[(p + 0) * 64 + 9 + f * 4 + 0] + Ub[(p + 1) * 64 + 9 + f * 4 + 1] +
                 Ub[(p + 2) * 64 + 9 + f * 4 + 2] + Ub[(p + 3) * 64 + 9 + f * 4 + 3];
  }
  if (p < 252) {
    #pragma unroll
    for (int f = 0; f < 3; ++f)
      v[6 + f] = Ub[(p + 0) * 64 + 21 + f * 5 + 0] + Ub[(p + 1) * 64 + 21 + f * 5 + 1] +
                 Ub[(p + 2) * 64 + 21 + f * 5 + 2] + Ub[(p + 3) * 64 + 21 + f * 5 + 3] +
                 Ub[(p + 4) * 64 + 21 + f * 5 + 4];
  }
  __shared__ float red[4][9];
  const int lane = threadIdx.x & 63, w = threadIdx.x >> 6;
  #pragma unroll
  for (int j = 0; j < 9; ++j) {
    float m = v[j];
    #pragma unroll
    for (int off = 32; off >= 1; off >>= 1) m = fmaxf(m, __shfl_xor(m, off));
    if (lane == 0) red[w][j] = m;
  }
  __syncthreads();
  if (threadIdx.x < 2) {
    const int k = threadIdx.x;
    float o = bl[k];
    #pragma unroll
    for (int j = 0; j < 9; ++j) {
      float m = fmaxf(fmaxf(red[0][j], red[1][j]), fmaxf(red[2][j], red[3][j]));
      float bias = (j < 3) ? bc3[j] : (j < 6) ? bc4[j - 3] : bc5[j - 6];
      o += fmaxf(m + bias, 0.0f) * Wl[j * 2 + k];
    }
    out[b * 2 + k] = o;
  }
}

// ---------------- host launch ----------------
extern "C" void kernel_launch(void* const* d_in, const int* in_sizes, int n_in,
                              void* d_out, int out_size, void* d_ws, size_t ws_size,
                              hipStream_t stream) {
  const float* x     = (const float*)d_in[0];
  const float* W_in  = (const float*)d_in[1];
  const float* b_in  = (const float*)d_in[2];
  const float* Wih   = (const float*)d_in[3];
  const float* Whh   = (const float*)d_in[4];
  const float* bih   = (const float*)d_in[5];
  const float* bhh   = (const float*)d_in[6];
  const float* Q     = (const float*)d_in[7];
  const float* R     = (const float*)d_in[8];
  const float* Wc3   = (const float*)d_in[9];
  const float* bc3   = (const float*)d_in[10];
  const float* Wc4   = (const float*)d_in[11];
  const float* bc4   = (const float*)d_in[12];
  const float* Wc5   = (const float*)d_in[13];
  const float* bc5   = (const float*)d_in[14];
  const float* W_lin = (const float*)d_in[15];
  const float* b_lin = (const float*)d_in[16];

  if (ws_size < WS_NEED) {  // diagnosable marker: absmax ≈ ws_size in MB
    k_wsfail<<<4, 256, 0, stream>>>((float*)d_out, out_size, (float)(ws_size >> 20));
    return;
  }

  char* ws = (char*)d_ws;
  unsigned short* xin = (unsigned short*)(ws + OFF_XIN);
  float*          U   = (float*)(ws + OFF_U);
  unsigned short* hs  = (unsigned short*)(ws + OFF_HS);
  unsigned short* act = (unsigned short*)(ws + OFF_ACT);
  float*          hfp = (float*)(ws + OFF_HFP);
  unsigned short* WpT = (unsigned short*)(ws + OFF_WPT);
  unsigned short* QpT = (unsigned short*)(ws + OFF_QPT);
  unsigned short* RpT = (unsigned short*)(ws + OFF_RPT);
  unsigned short* WgT = (unsigned short*)(ws + OFF_WGT);
  float*          bg  = (float*)(ws + OFF_BG);
  unsigned short* VT  = (unsigned short*)(ws + OFF_VT);
  unsigned int*   bar = (unsigned int*)(ws + OFF_BAR);

  // per-replay init: h0 = c0 = 0, barrier counters = 0
  (void)hipMemsetAsync(hs, 0, HSLOT * 2, stream);   // ring slot 0
  (void)hipMemsetAsync(hfp, 0, SZ_HFP, stream);
  (void)hipMemsetAsync(bar, 0, SZ_BAR, stream);

  // weight prep
  k_prep_wpt<<<(320 * 320 + 255) / 256, 256, 0, stream>>>(W_in, WpT);
  k_prep_qpt<<<(320 * 512 + 255) / 256, 256, 0, stream>>>(Q, QpT);
  k_prep_rpt<<<(512 * 320 + 255) / 256, 256, 0, stream>>>(R, RpT);
  k_prep_wgt<<<(2048 * 832 + 255) / 256, 256, 0, stream>>>(Wih, Whh, WgT);
  k_prep_bg<<<8, 256, 0, stream>>>(bih, bhh, bg);
  k_prep_vt<<<(64 * 512 + 255) / 256, 256, 0, stream>>>(Wc3, Wc4, Wc5, VT);

  // input projection
  k_proj<<<dim3(131072 / 64, KP_ / 64), 256, 0, stream>>>(x, WpT, b_in, xin);

  // persistent scan (entire 256-step recurrence in one dispatch)
  k_scan<<<NWG, 256, 0, stream>>>(xin, QpT, RpT, WgT, bg, VT, hs, act, hfp, U, bar);

  // conv window-max + final linear
  k_combine<<<512, 256, 0, stream>>>(U, bc3, bc4, bc5, W_lin, b_lin, (float*)d_out);
}

// Round 5
// 6764.040 us; speedup vs baseline: 2.7699x; 2.7699x over previous
//
#include <hip/hip_runtime.h>

#define DI __device__ __forceinline__

typedef __attribute__((ext_vector_type(4))) float  f32x4;
typedef __attribute__((ext_vector_type(8))) short  s16x8;
typedef __attribute__((ext_vector_type(8))) __bf16 bf16x8;

// ---------------- constants ----------------
constexpr int S_   = 256;
constexpr int B_   = 512;
constexpr int H_   = 512;
constexpr int KP_  = 320;   // padded 300
constexpr int ALD_ = 832;   // act row: [xt 0..320 | htm 320..832]
constexpr int NRING = 34;
constexpr int NWG  = 256;   // persistent workgroups (== CU count)
constexpr size_t HSLOT = 512 * 512;  // elements per hs slot

// ---------------- workspace layout (bytes) ----------------
constexpr size_t OFF_XIN = 0;                              // bf16 [S][B][320]
constexpr size_t SZ_XIN  = (size_t)S_ * B_ * KP_ * 2;
constexpr size_t OFF_U   = OFF_XIN + SZ_XIN;               // f32 [B][S][64]
constexpr size_t SZ_U    = (size_t)B_ * S_ * 64 * 4;
constexpr size_t OFF_HS  = OFF_U + SZ_U;                   // bf16 ring [34][512][512]
constexpr size_t SZ_HS   = (size_t)NRING * HSLOT * 2;
constexpr size_t OFF_ACT = OFF_HS + SZ_HS;                 // bf16 [512][832]
constexpr size_t SZ_ACT  = (size_t)B_ * ALD_ * 2;
constexpr size_t OFF_HFP = OFF_ACT + SZ_ACT;               // f32 [512][512]
constexpr size_t SZ_HFP  = (size_t)B_ * H_ * 4;
constexpr size_t OFF_WPT = OFF_HFP + SZ_HFP;               // bf16 [320][320]
constexpr size_t SZ_WPT  = (size_t)320 * 320 * 2;
constexpr size_t OFF_QPT = OFF_WPT + SZ_WPT;               // bf16 [320][512]
constexpr size_t SZ_QPT  = (size_t)320 * 512 * 2;
constexpr size_t OFF_RPT = OFF_QPT + SZ_QPT;               // bf16 [512][320]
constexpr size_t SZ_RPT  = (size_t)512 * 320 * 2;
constexpr size_t OFF_WGT = OFF_RPT + SZ_RPT;               // bf16 [2048][832]
constexpr size_t SZ_WGT  = (size_t)2048 * 832 * 2;
constexpr size_t OFF_BG  = OFF_WGT + SZ_WGT;               // f32 [2048]
constexpr size_t SZ_BG   = 2048 * 4;
constexpr size_t OFF_VT  = OFF_BG + SZ_BG;                 // bf16 [64][512]
constexpr size_t SZ_VT   = (size_t)64 * 512 * 2;
constexpr size_t OFF_BAR = OFF_VT + SZ_VT;                 // u32 barrier counters
constexpr size_t SZ_BAR  = 4096;
constexpr size_t WS_NEED = OFF_BAR + SZ_BAR;

// ---------------- helpers ----------------
DI unsigned short f2bf(float x) {
  unsigned int u = __float_as_uint(x);
  unsigned int r = (u + 0x7FFFu + ((u >> 16) & 1u)) >> 16;
  return (unsigned short)r;
}
DI float bf2f(unsigned short h) { return __uint_as_float(((unsigned int)h) << 16); }

DI float sigm(float x) {
  float e = __builtin_amdgcn_exp2f(x * -1.44269504088896f);
  return __builtin_amdgcn_rcpf(1.0f + e);
}
DI float tanh_(float x) {
  x = fminf(fmaxf(x, -15.0f), 15.0f);
  float e = __builtin_amdgcn_exp2f(x * 2.88539008177793f);
  return (e - 1.0f) * __builtin_amdgcn_rcpf(e + 1.0f);
}
DI bf16x8 asbf(s16x8 v) { return __builtin_bit_cast(bf16x8, v); }

// ---- LLC-coherent (sc0 sc1) accesses, compiler-managed (no inline asm) ----
DI unsigned long long ld_sys_u64(const void* p) {
  return __hip_atomic_load((const unsigned long long*)p, __ATOMIC_RELAXED,
                           __HIP_MEMORY_SCOPE_SYSTEM);
}
DI void st_sys_u64(void* p, unsigned long long v) {
  __hip_atomic_store((unsigned long long*)p, v, __ATOMIC_RELAXED,
                     __HIP_MEMORY_SCOPE_SYSTEM);
}
template<int N> DI void wait_vm() {          // pure wait, no outputs: hazard-free
  asm volatile("s_waitcnt vmcnt(%0)" :: "n"(N) : "memory");
}

struct a16x8 { unsigned long long lo, hi; };   // 16 bytes of A-operand
DI a16x8 ldA(const unsigned short* p) {
  a16x8 r; r.lo = ld_sys_u64(p); r.hi = ld_sys_u64(p + 4); return r;
}
DI void stA_lds(short* dst, a16x8 v) {
  *(unsigned long long*)dst = v.lo; *(unsigned long long*)(dst + 4) = v.hi;
}

// ---------------- GEMM core (A system-coherent, B cached weights) ----------
// A: row-major [64][lda] bf16 via sc0sc1 u64 loads (depth-2 reg prefetch).
// B: row-major B^T [64][ldb] bf16, plain cached (L2-hot weights).
// 256 threads, 4 waves 2x2, wave tile 32x32 (2x2 16x16x32 frags). LDS dbuf.
template<int NK>
DI void gemm_sys(const unsigned short* Ab, int lda,
                 const unsigned short* Bb, int ldb,
                 short* sA, short* sB, f32x4 acc[2][2])
{
  const int tid  = threadIdx.x;
  const int lane = tid & 63;
  const int w = tid >> 6, wm = w >> 1, wn = w & 1;
  const unsigned short* ga = Ab + (tid >> 2) * lda + (tid & 3) * 8;
  const unsigned short* gb = Bb + (tid >> 2) * ldb + (tid & 3) * 8;
  const int arow0 = (wm * 32 + (lane & 15)) * 32 + (lane >> 4) * 8;
  const int brow0 = (wn * 32 + (lane & 15)) * 32 + (lane >> 4) * 8;

  a16x8 a0 = ldA(ga), a1 = {};
  s16x8 b0 = *(const s16x8*)gb, b1 = {};
  if (NK > 1) { a1 = ldA(ga + 32); b1 = *(const s16x8*)(gb + 32); }
  stA_lds(&sA[tid * 8], a0);
  *(s16x8*)&sB[tid * 8] = b0;
  __syncthreads();
  #pragma unroll
  for (int k = 0; k < NK; ++k) {
    const int cur = (k & 1) * 2048;
    if (k + 2 < NK) {   // tile j=k+2 goes to reg set of parity j&1 == k&1
      if ((k & 1) == 0) { a0 = ldA(ga + (k + 2) * 32); b0 = *(const s16x8*)(gb + (k + 2) * 32); }
      else              { a1 = ldA(ga + (k + 2) * 32); b1 = *(const s16x8*)(gb + (k + 2) * 32); }
    }
    s16x8 A0 = *(const s16x8*)&sA[cur + arow0];
    s16x8 A1 = *(const s16x8*)&sA[cur + arow0 + 16 * 32];
    s16x8 B0 = *(const s16x8*)&sB[cur + brow0];
    s16x8 B1 = *(const s16x8*)&sB[cur + brow0 + 16 * 32];
    acc[0][0] = __builtin_amdgcn_mfma_f32_16x16x32_bf16(asbf(A0), asbf(B0), acc[0][0], 0, 0, 0);
    acc[0][1] = __builtin_amdgcn_mfma_f32_16x16x32_bf16(asbf(A0), asbf(B1), acc[0][1], 0, 0, 0);
    acc[1][0] = __builtin_amdgcn_mfma_f32_16x16x32_bf16(asbf(A1), asbf(B0), acc[1][0], 0, 0, 0);
    acc[1][1] = __builtin_amdgcn_mfma_f32_16x16x32_bf16(asbf(A1), asbf(B1), acc[1][1], 0, 0, 0);
    if (k + 1 < NK) {   // tile j=k+1 lives in reg set parity (k+1)&1
      const int nxt = ((k + 1) & 1) * 2048;
      if ((k & 1) == 0) { stA_lds(&sA[nxt + tid * 8], a1); *(s16x8*)&sB[nxt + tid * 8] = b1; }
      else              { stA_lds(&sA[nxt + tid * 8], a0); *(s16x8*)&sB[nxt + tid * 8] = b0; }
    }
    __syncthreads();
  }
}

// Variant: A is fp32 (normal cached), K real = KREAL. Used by k_proj only.
template<int NK, int KREAL>
DI void gemm_f32A(const float* Af, int lda,
                  const unsigned short* Bb, int ldb,
                  short* sA, short* sB, f32x4 acc[2][2])
{
  const int tid  = threadIdx.x;
  const int lane = tid & 63;
  const int w = tid >> 6, wm = w >> 1, wn = w & 1;
  const float* ga = Af + (tid >> 2) * lda;
  const int cseg  = (tid & 3) * 8;
  const unsigned short* gb = Bb + (tid >> 2) * ldb + (tid & 3) * 8;
  const int arow0 = (wm * 32 + (lane & 15)) * 32 + (lane >> 4) * 8;
  const int brow0 = (wn * 32 + (lane & 15)) * 32 + (lane >> 4) * 8;

  auto loadA = [&](int k) -> s16x8 {
    s16x8 r;
    const int c0 = k * 32 + cseg;
    if (c0 + 8 <= KREAL) {
      float4 f0 = *(const float4*)(ga + c0);
      float4 f1 = *(const float4*)(ga + c0 + 4);
      r[0] = (short)f2bf(f0.x); r[1] = (short)f2bf(f0.y);
      r[2] = (short)f2bf(f0.z); r[3] = (short)f2bf(f0.w);
      r[4] = (short)f2bf(f1.x); r[5] = (short)f2bf(f1.y);
      r[6] = (short)f2bf(f1.z); r[7] = (short)f2bf(f1.w);
    } else {
      #pragma unroll
      for (int j = 0; j < 8; ++j) {
        float x = (c0 + j < KREAL) ? ga[c0 + j] : 0.0f;
        r[j] = (short)f2bf(x);
      }
    }
    return r;
  };

  s16x8 va = loadA(0);
  s16x8 vb = *(const s16x8*)gb;
  *(s16x8*)&sA[tid * 8] = va;
  *(s16x8*)&sB[tid * 8] = vb;
  __syncthreads();
  for (int k = 0; k < NK; ++k) {
    const int cur = (k & 1) * 2048;
    if (k + 1 < NK) {
      va = loadA(k + 1);
      vb = *(const s16x8*)(gb + (k + 1) * 32);
    }
    s16x8 a0 = *(const s16x8*)&sA[cur + arow0];
    s16x8 a1 = *(const s16x8*)&sA[cur + arow0 + 16 * 32];
    s16x8 b0 = *(const s16x8*)&sB[cur + brow0];
    s16x8 b1 = *(const s16x8*)&sB[cur + brow0 + 16 * 32];
    acc[0][0] = __builtin_amdgcn_mfma_f32_16x16x32_bf16(asbf(a0), asbf(b0), acc[0][0], 0, 0, 0);
    acc[0][1] = __builtin_amdgcn_mfma_f32_16x16x32_bf16(asbf(a0), asbf(b1), acc[0][1], 0, 0, 0);
    acc[1][0] = __builtin_amdgcn_mfma_f32_16x16x32_bf16(asbf(a1), asbf(b0), acc[1][0], 0, 0, 0);
    acc[1][1] = __builtin_amdgcn_mfma_f32_16x16x32_bf16(asbf(a1), asbf(b1), acc[1][1], 0, 0, 0);
    if (k + 1 < NK) {
      const int nxt = ((k + 1) & 1) * 2048;
      *(s16x8*)&sA[nxt + tid * 8] = va;
      *(s16x8*)&sB[nxt + tid * 8] = vb;
    }
    __syncthreads();
  }
}

// epilogue iterator: f(rowl, coll, acc_value) for the 64x64 block tile
template<typename F>
DI void epiloop(f32x4 acc[2][2], F&& f) {
  const int lane = threadIdx.x & 63;
  const int w = threadIdx.x >> 6, wm = w >> 1, wn = w & 1;
  #pragma unroll
  for (int mi = 0; mi < 2; ++mi)
    #pragma unroll
    for (int ni = 0; ni < 2; ++ni)
      #pragma unroll
      for (int r = 0; r < 4; ++r) {
        const int rowl = wm * 32 + mi * 16 + (lane >> 4) * 4 + r;
        const int coll = wn * 32 + ni * 16 + (lane & 15);
        f(rowl, coll, acc[mi][ni][r]);
      }
}

// pack-store a 64x64 u16 LDS tile to system memory as u64s (16 per row)
DI void pack_store_tile(const unsigned short* lds16, unsigned short* dstbase, int ldd) {
  const unsigned long long* l64 = (const unsigned long long*)lds16;
  #pragma unroll
  for (int it = 0; it < 4; ++it) {
    const int i = it * 256 + threadIdx.x;
    const int row = i >> 4, q = i & 15;
    st_sys_u64(dstbase + row * ldd + q * 4, l64[row * 16 + q]);
  }
}

// ---------------- prep kernels ----------------
__global__ void k_prep_wpt(const float* __restrict__ Wi, unsigned short* __restrict__ WpT) {
  int i = blockIdx.x * 256 + threadIdx.x;
  if (i >= 320 * 320) return;
  int n = i / 320, k = i % 320;
  float v = (n < 300 && k < 300) ? Wi[k * 300 + n] : 0.0f;
  WpT[i] = f2bf(v);
}
__global__ void k_prep_qpt(const float* __restrict__ Q, unsigned short* __restrict__ QpT) {
  int i = blockIdx.x * 256 + threadIdx.x;
  if (i >= 320 * 512) return;
  int n = i >> 9, k = i & 511;
  float v = (n < 300) ? Q[k * 300 + n] : 0.0f;
  QpT[i] = f2bf(v);
}
__global__ void k_prep_rpt(const float* __restrict__ R, unsigned short* __restrict__ RpT) {
  int i = blockIdx.x * 256 + threadIdx.x;
  if (i >= 512 * 320) return;
  int n = i / 320, k = i % 320;
  float v = (k < 300) ? R[k * 512 + n] : 0.0f;
  RpT[i] = f2bf(v);
}
__global__ void k_prep_wgt(const float* __restrict__ Wih, const float* __restrict__ Whh,
                           unsigned short* __restrict__ WgT) {
  int i = blockIdx.x * 256 + threadIdx.x;
  if (i >= 2048 * 832) return;
  int np = i / 832, k = i % 832;
  int c = np >> 2, g = np & 3, col = g * 512 + c;
  float v = 0.0f;
  if (k < 300) v = Wih[k * 2048 + col];
  else if (k >= 320) v = Whh[(k - 320) * 2048 + col];
  WgT[i] = f2bf(v);
}
__global__ void k_prep_bg(const float* __restrict__ bih, const float* __restrict__ bhh,
                          float* __restrict__ bg) {
  int i = blockIdx.x * 256 + threadIdx.x;
  if (i >= 2048) return;
  int c = i >> 2, g = i & 3, col = g * 512 + c;
  bg[i] = bih[col] + bhh[col];
}
__global__ void k_prep_vt(const float* __restrict__ Wc3, const float* __restrict__ Wc4,
                          const float* __restrict__ Wc5, unsigned short* __restrict__ VT) {
  int i = blockIdx.x * 256 + threadIdx.x;
  if (i >= 64 * 512) return;
  int j = i >> 9, k = i & 511;
  float v = 0.0f;
  if (j < 9)       { int f = j / 3,  dt = j % 3;        v = Wc3[(f * 3 + dt) * 512 + k]; }
  else if (j < 21) { int jj = j - 9;  int f = jj / 4, dt = jj % 4; v = Wc4[(f * 4 + dt) * 512 + k]; }
  else if (j < 36) { int jj = j - 21; int f = jj / 5, dt = jj % 5; v = Wc5[(f * 5 + dt) * 512 + k]; }
  VT[i] = f2bf(v);
}
__global__ void k_wsfail(float* out, int n, float v) {
  int i = blockIdx.x * 256 + threadIdx.x;
  if (i < n) out[i] = -v;
}

// ---------------- input projection ----------------
__global__ __launch_bounds__(256) void k_proj(const float* __restrict__ x,
                                              const unsigned short* __restrict__ WpT,
                                              const float* __restrict__ b_in,
                                              unsigned short* __restrict__ xin) {
  __shared__ short sA[4096], sB[4096];
  const int m0 = blockIdx.x * 64, n0 = blockIdx.y * 64;
  f32x4 acc[2][2];
  const f32x4 z = {0.f, 0.f, 0.f, 0.f};
  acc[0][0] = z; acc[0][1] = z; acc[1][0] = z; acc[1][1] = z;
  gemm_f32A<10, 300>(x + (size_t)m0 * 300, 300, WpT + n0 * 320, 320, sA, sB, acc);
  epiloop(acc, [&](int rowl, int coll, float vacc) {
    const int row = m0 + rowl, col = n0 + coll;
    float o = 0.0f;
    if (col < 300) o = tanh_(vacc + b_in[col]);
    const int b = row >> 8, s = row & 255;
    xin[(size_t)(s * 512 + b) * KP_ + col] = f2bf(o);
  });
}

// ---------------- persistent scan kernel ----------------
// 256 WGs x 256 threads. Cross-WG data (act, hs, hfp) moves ONLY through
// system-scope (sc0sc1, LLC-coherent) atomic loads/stores -> no cache fences,
// weights stay L2-hot. Barrier: two-level relaxed atomics + vmcnt(0) drain.
__global__ __launch_bounds__(256) void k_scan(
    const unsigned short* __restrict__ xin,
    const unsigned short* __restrict__ QpT,
    const unsigned short* __restrict__ RpT,
    const unsigned short* __restrict__ WgT,
    const float* __restrict__ bg,
    const unsigned short* __restrict__ VT,
    unsigned short* __restrict__ hs,
    unsigned short* __restrict__ act,
    float* __restrict__ hfp,
    float* __restrict__ U,
    unsigned int* __restrict__ bar)
{
  __shared__ short sA[4096], sB[4096];
  __shared__ float gbuf[4096];
  const int wg  = blockIdx.x;
  const int tid = threadIdx.x;
  const f32x4 z = {0.f, 0.f, 0.f, 0.f};

  // gates tile assignment (static across steps -> cell state in registers)
  const int gm0 = (wg >> 5) * 64;       // batch-row tile
  const int gn0 = (wg & 31) * 64;       // gate-col tile (permuted n' = 4c+g)
  float c_state[4] = {0.f, 0.f, 0.f, 0.f};

  int ep = 0;  // barrier epoch
  auto bar_sync = [&]() {
    wait_vm<0>();        // each wave drains its own system-stores to LLC
    __syncthreads();
    if (tid == 0) {
      unsigned old = __hip_atomic_fetch_add(&bar[(wg >> 4) * 32], 1u,
                                            __ATOMIC_RELAXED, __HIP_MEMORY_SCOPE_AGENT);
      if (old == (unsigned)ep * 16u + 15u)
        __hip_atomic_fetch_add(&bar[512], 1u, __ATOMIC_RELAXED, __HIP_MEMORY_SCOPE_AGENT);
      const unsigned tgt = (unsigned)(ep + 1) * 16u;
      while (__hip_atomic_load(&bar[512], __ATOMIC_RELAXED, __HIP_MEMORY_SCOPE_AGENT) < tgt)
        __builtin_amdgcn_s_sleep(2);
    }
    __syncthreads();
    ++ep;
  };

  for (int t = 0; t < S_; ++t) {
    const unsigned short* hst = hs + (size_t)(t % NRING) * HSLOT;
    unsigned short*       hso = hs + (size_t)((t + 1) % NRING) * HSLOT;

    // ---- P1: act[:,0:320] = 2*sigm(h_{t-1} @ Q) * xin_t  (40 tiles)
    if (wg < 40) {
      const int m0 = (wg / 5) * 64, n0 = (wg % 5) * 64;
      f32x4 acc[2][2];
      acc[0][0] = z; acc[0][1] = z; acc[1][0] = z; acc[1][1] = z;
      gemm_sys<16>(hst + m0 * 512, 512, QpT + n0 * 512, 512, sA, sB, acc);
      const unsigned short* xin_t = xin + (size_t)t * 512 * KP_;
      unsigned short* g16 = (unsigned short*)gbuf;
      epiloop(acc, [&](int rowl, int coll, float vacc) {
        const int row = m0 + rowl, col = n0 + coll;
        g16[rowl * 64 + coll] = f2bf(2.0f * sigm(vacc) * bf2f(xin_t[row * KP_ + col]));
      });
      __syncthreads();
      pack_store_tile(g16, act + m0 * ALD_ + n0, ALD_);
    }
    bar_sync();

    // ---- P2: act[:,320:832] = 2*sigm(xt @ R) * hfp  (64 tiles)
    if (wg < 64) {
      const int m0 = (wg >> 3) * 64, n0 = (wg & 7) * 64;
      // cooperative hfp tile load into gbuf (latency hides under the GEMM)
      unsigned long long* g64 = (unsigned long long*)gbuf;
      #pragma unroll
      for (int it = 0; it < 8; ++it) {
        const int i = it * 256 + tid;
        const int row = i >> 5, p = i & 31;
        g64[row * 32 + p] = ld_sys_u64(hfp + (m0 + row) * 512 + n0 + p * 2);
      }
      f32x4 acc[2][2];
      acc[0][0] = z; acc[0][1] = z; acc[1][0] = z; acc[1][1] = z;
      gemm_sys<10>(act + m0 * ALD_, ALD_, RpT + n0 * KP_, KP_, sA, sB, acc);
      unsigned short* g16 = (unsigned short*)sA;   // sA free after gemm
      epiloop(acc, [&](int rowl, int coll, float vacc) {
        g16[rowl * 64 + coll] = f2bf(2.0f * sigm(vacc) * gbuf[rowl * 64 + coll]);
      });
      __syncthreads();
      pack_store_tile(g16, act + m0 * ALD_ + 320 + n0, ALD_);
    }
    bar_sync();

    // ---- P3: gates GEMM + cell update (256 tiles, Ct in registers)
    {
      f32x4 acc[2][2];
      acc[0][0] = z; acc[0][1] = z; acc[1][0] = z; acc[1][1] = z;
      gemm_sys<26>(act + gm0 * ALD_, ALD_, WgT + gn0 * 832, 832, sA, sB, acc);
      epiloop(acc, [&](int rowl, int coll, float vacc) {
        gbuf[rowl * 64 + coll] = vacc;
      });
      unsigned short* hbuf = (unsigned short*)sA;  // 64x16 u16 (free after gemm)
      float*          fbuf = (float*)sB;           // 64x16 f32
      __syncthreads();
      #pragma unroll
      for (int q = 0; q < 4; ++q) {
        const int item = q * 256 + tid;
        const int row = item >> 4, cu = item & 15;
        const float4 bb = *(const float4*)&bg[gn0 + cu * 4];
        const float iv = gbuf[row * 64 + cu * 4 + 0] + bb.x;
        const float fv = gbuf[row * 64 + cu * 4 + 1] + bb.y;
        const float gv = gbuf[row * 64 + cu * 4 + 2] + bb.z;
        const float ov = gbuf[row * 64 + cu * 4 + 3] + bb.w;
        const float cn = sigm(fv) * c_state[q] + sigm(iv) * tanh_(gv);
        const float h  = sigm(ov) * tanh_(cn);
        c_state[q] = cn;
        hbuf[row * 16 + cu] = f2bf(h);
        fbuf[row * 16 + cu] = h;
      }
      __syncthreads();
      // pack-store h (64x16 u16 = 256 u64) and hfp (64x16 f32 = 512 u64)
      {
        const unsigned long long* h64 = (const unsigned long long*)hbuf;
        const int row = tid >> 2, q = tid & 3;
        st_sys_u64(hso + (gm0 + row) * 512 + (gn0 >> 2) + q * 4, h64[row * 4 + q]);
        const unsigned long long* f64 = (const unsigned long long*)fbuf;
        #pragma unroll
        for (int it = 0; it < 2; ++it) {
          const int i = it * 256 + tid;
          const int r2 = i >> 3, p = i & 7;
          st_sys_u64(hfp + (gm0 + r2) * 512 + (gn0 >> 2) + p * 2, f64[r2 * 8 + p]);
        }
      }
      __syncthreads();
    }
    bar_sync();

    // ---- convU every 32 steps (ring slack, no extra barrier needed)
    if ((t & 31) == 31) {
      const int c = t >> 5;
      const int m0c = wg * 64;
      const int tglob = 32 * c + (m0c >> 9);
      const int slot = (tglob + 1) % NRING;
      const int brow = m0c & 511;
      f32x4 acc[2][2];
      acc[0][0] = z; acc[0][1] = z; acc[1][0] = z; acc[1][1] = z;
      gemm_sys<16>(hs + (size_t)slot * HSLOT + (size_t)brow * 512, 512, VT, 512, sA, sB, acc);
      epiloop(acc, [&](int rowl, int coll, float vacc) {
        U[((size_t)(brow + rowl) * 256 + tglob) * 64 + coll] = vacc;
      });
    }
  }
}

// window-sum + relu + global max pool + final linear
__global__ __launch_bounds__(256) void k_combine(const float* __restrict__ U,
                                                 const float* __restrict__ bc3,
                                                 const float* __restrict__ bc4,
                                                 const float* __restrict__ bc5,
                                                 const float* __restrict__ Wl,
                                                 const float* __restrict__ bl,
                                                 float* __restrict__ out) {
  const int b = blockIdx.x;
  const int p = threadIdx.x;
  const float* Ub = U + (size_t)b * (256 * 64);
  float v[9];
  #pragma unroll
  for (int j = 0; j < 9; ++j) v[j] = -1e30f;
  if (p < 254) {
    #pragma unroll
    for (int f = 0; f < 3; ++f)
      v[f] = Ub[(p + 0) * 64 + f * 3 + 0] + Ub[(p + 1) * 64 + f * 3 + 1] + Ub[(p + 2) * 64 + f * 3 + 2];
  }
  if (p < 253) {
    #pragma unroll
    for (int f = 0; f < 3; ++f)
      v[3 + f] = Ub[(p + 0) * 64 + 9 + f * 4 + 0] + Ub[(p + 1) * 64 + 9 + f * 4 + 1] +
                 Ub[(p + 2) * 64 + 9 + f * 4 + 2] + Ub[(p + 3) * 64 + 9 + f * 4 + 3];
  }
  if (p < 252) {
    #pragma unroll
    for (int f = 0; f < 3; ++f)
      v[6 + f] = Ub[(p + 0) * 64 + 21 + f * 5 + 0] + Ub[(p + 1) * 64 + 21 + f * 5 + 1] +
                 Ub[(p + 2) * 64 + 21 + f * 5 + 2] + Ub[(p + 3) * 64 + 21 + f * 5 + 3] +
                 Ub[(p + 4) * 64 + 21 + f * 5 + 4];
  }
  __shared__ float red[4][9];
  const int lane = threadIdx.x & 63, w = threadIdx.x >> 6;
  #pragma unroll
  for (int j = 0; j < 9; ++j) {
    float m = v[j];
    #pragma unroll
    for (int off = 32; off >= 1; off >>= 1) m = fmaxf(m, __shfl_xor(m, off));
    if (lane == 0) red[w][j] = m;
  }
  __syncthreads();
  if (threadIdx.x < 2) {
    const int k = threadIdx.x;
    float o = bl[k];
    #pragma unroll
    for (int j = 0; j < 9; ++j) {
      float m = fmaxf(fmaxf(red[0][j], red[1][j]), fmaxf(red[2][j], red[3][j]));
      float bias = (j < 3) ? bc3[j] : (j < 6) ? bc4[j - 3] : bc5[j - 6];
      o += fmaxf(m + bias, 0.0f) * Wl[j * 2 + k];
    }
    out[b * 2 + k] = o;
  }
}

// ---------------- host launch ----------------
extern "C" void kernel_launch(void* const* d_in, const int* in_sizes, int n_in,
                              void* d_out, int out_size, void* d_ws, size_t ws_size,
                              hipStream_t stream) {
  const float* x     = (const float*)d_in[0];
  const float* W_in  = (const float*)d_in[1];
  const float* b_in  = (const float*)d_in[2];
  const float* Wih   = (const float*)d_in[3];
  const float* Whh   = (const float*)d_in[4];
  const float* bih   = (const float*)d_in[5];
  const float* bhh   = (const float*)d_in[6];
  const float* Q     = (const float*)d_in[7];
  const float* R     = (const float*)d_in[8];
  const float* Wc3   = (const float*)d_in[9];
  const float* bc3   = (const float*)d_in[10];
  const float* Wc4   = (const float*)d_in[11];
  const float* bc4   = (const float*)d_in[12];
  const float* Wc5   = (const float*)d_in[13];
  const float* bc5   = (const float*)d_in[14];
  const float* W_lin = (const float*)d_in[15];
  const float* b_lin = (const float*)d_in[16];

  if (ws_size < WS_NEED) {  // diagnosable marker: absmax ≈ ws_size in MB
    k_wsfail<<<4, 256, 0, stream>>>((float*)d_out, out_size, (float)(ws_size >> 20));
    return;
  }

  char* ws = (char*)d_ws;
  unsigned short* xin = (unsigned short*)(ws + OFF_XIN);
  float*          U   = (float*)(ws + OFF_U);
  unsigned short* hs  = (unsigned short*)(ws + OFF_HS);
  unsigned short* act = (unsigned short*)(ws + OFF_ACT);
  float*          hfp = (float*)(ws + OFF_HFP);
  unsigned short* WpT = (unsigned short*)(ws + OFF_WPT);
  unsigned short* QpT = (unsigned short*)(ws + OFF_QPT);
  unsigned short* RpT = (unsigned short*)(ws + OFF_RPT);
  unsigned short* WgT = (unsigned short*)(ws + OFF_WGT);
  float*          bg  = (float*)(ws + OFF_BG);
  unsigned short* VT  = (unsigned short*)(ws + OFF_VT);
  unsigned int*   bar = (unsigned int*)(ws + OFF_BAR);

  // per-replay init: h0 = c0 = 0 (ring slot 0 + hfp), barrier counters = 0
  (void)hipMemsetAsync(hs, 0, HSLOT * 2, stream);
  (void)hipMemsetAsync(hfp, 0, SZ_HFP, stream);
  (void)hipMemsetAsync(bar, 0, SZ_BAR, stream);

  // weight prep
  k_prep_wpt<<<(320 * 320 + 255) / 256, 256, 0, stream>>>(W_in, WpT);
  k_prep_qpt<<<(320 * 512 + 255) / 256, 256, 0, stream>>>(Q, QpT);
  k_prep_rpt<<<(512 * 320 + 255) / 256, 256, 0, stream>>>(R, RpT);
  k_prep_wgt<<<(2048 * 832 + 255) / 256, 256, 0, stream>>>(Wih, Whh, WgT);
  k_prep_bg<<<8, 256, 0, stream>>>(bih, bhh, bg);
  k_prep_vt<<<(64 * 512 + 255) / 256, 256, 0, stream>>>(Wc3, Wc4, Wc5, VT);

  // input projection
  k_proj<<<dim3(131072 / 64, KP_ / 64), 256, 0, stream>>>(x, WpT, b_in, xin);

  // persistent scan (entire 256-step recurrence in one dispatch)
  k_scan<<<NWG, 256, 0, stream>>>(xin, QpT, RpT, WgT, bg, VT, hs, act, hfp, U, bar);

  // conv window-max + final linear
  k_combine<<<512, 256, 0, stream>>>(U, bc3, bc4, bc5, W_lin, b_lin, (float*)d_out);
}

// Round 6
// 6144.369 us; speedup vs baseline: 3.0492x; 1.1009x over previous
//
#include <hip/hip_runtime.h>

#define DI __device__ __forceinline__

typedef __attribute__((ext_vector_type(4))) float  f32x4;
typedef __attribute__((ext_vector_type(8))) short  s16x8;
typedef __attribute__((ext_vector_type(8))) __bf16 bf16x8;

// ---------------- constants ----------------
constexpr int S_   = 256;
constexpr int B_   = 512;
constexpr int H_   = 512;
constexpr int KP_  = 320;   // padded 300
constexpr int ALD_ = 832;   // act row: [xt 0..320 | htm 320..832]
constexpr int NRING = 34;
constexpr int NWG  = 256;   // persistent workgroups (== CU count)
constexpr size_t HSLOT = 512 * 512;  // elements per hs slot

// ---------------- workspace layout (bytes) ----------------
constexpr size_t OFF_XIN = 0;                              // bf16 [S][B][320]
constexpr size_t SZ_XIN  = (size_t)S_ * B_ * KP_ * 2;
constexpr size_t OFF_U   = OFF_XIN + SZ_XIN;               // f32 [B][S][64]
constexpr size_t SZ_U    = (size_t)B_ * S_ * 64 * 4;
constexpr size_t OFF_HS  = OFF_U + SZ_U;                   // bf16 ring [34][512][512]
constexpr size_t SZ_HS   = (size_t)NRING * HSLOT * 2;
constexpr size_t OFF_ACT = OFF_HS + SZ_HS;                 // bf16 [512][832]
constexpr size_t SZ_ACT  = (size_t)B_ * ALD_ * 2;
constexpr size_t OFF_HFP = OFF_ACT + SZ_ACT;               // f32 [512][512]
constexpr size_t SZ_HFP  = (size_t)B_ * H_ * 4;
constexpr size_t OFF_WPT = OFF_HFP + SZ_HFP;               // bf16 [320][320]
constexpr size_t SZ_WPT  = (size_t)320 * 320 * 2;
constexpr size_t OFF_QPT = OFF_WPT + SZ_WPT;               // bf16 [320][512]
constexpr size_t SZ_QPT  = (size_t)320 * 512 * 2;
constexpr size_t OFF_RPT = OFF_QPT + SZ_QPT;               // bf16 [512][320]
constexpr size_t SZ_RPT  = (size_t)512 * 320 * 2;
constexpr size_t OFF_WGT = OFF_RPT + SZ_RPT;               // bf16 [2048][832]
constexpr size_t SZ_WGT  = (size_t)2048 * 832 * 2;
constexpr size_t OFF_BG  = OFF_WGT + SZ_WGT;               // f32 [2048]
constexpr size_t SZ_BG   = 2048 * 4;
constexpr size_t OFF_VT  = OFF_BG + SZ_BG;                 // bf16 [64][512]
constexpr size_t SZ_VT   = (size_t)64 * 512 * 2;
constexpr size_t OFF_BAR = OFF_VT + SZ_VT;                 // u32 barrier counters
constexpr size_t SZ_BAR  = 4096;
constexpr size_t WS_NEED = OFF_BAR + SZ_BAR;

// ---------------- helpers ----------------
DI unsigned short f2bf(float x) {
  unsigned int u = __float_as_uint(x);
  unsigned int r = (u + 0x7FFFu + ((u >> 16) & 1u)) >> 16;
  return (unsigned short)r;
}
DI float bf2f(unsigned short h) { return __uint_as_float(((unsigned int)h) << 16); }

DI float sigm(float x) {
  float e = __builtin_amdgcn_exp2f(x * -1.44269504088896f);
  return __builtin_amdgcn_rcpf(1.0f + e);
}
DI float tanh_(float x) {
  x = fminf(fmaxf(x, -15.0f), 15.0f);
  float e = __builtin_amdgcn_exp2f(x * 2.88539008177793f);
  return (e - 1.0f) * __builtin_amdgcn_rcpf(e + 1.0f);
}
DI bf16x8 asbf(s16x8 v) { return __builtin_bit_cast(bf16x8, v); }

// ---- LLC-coherent (sc0 sc1) accesses, compiler-managed (no inline asm) ----
DI unsigned long long ld_sys_u64(const void* p) {
  return __hip_atomic_load((const unsigned long long*)p, __ATOMIC_RELAXED,
                           __HIP_MEMORY_SCOPE_SYSTEM);
}
DI void st_sys_u64(void* p, unsigned long long v) {
  __hip_atomic_store((unsigned long long*)p, v, __ATOMIC_RELAXED,
                     __HIP_MEMORY_SCOPE_SYSTEM);
}
template<int N> DI void wait_vm() {          // pure wait, no outputs: hazard-free
  asm volatile("s_waitcnt vmcnt(%0)" :: "n"(N) : "memory");
}

struct a16x8 { unsigned long long lo, hi; };   // 16 bytes of A-operand
DI a16x8 ldA(const unsigned short* p) {
  a16x8 r; r.lo = ld_sys_u64(p); r.hi = ld_sys_u64(p + 4); return r;
}
DI void stA_lds(short* dst, a16x8 v) {
  *(unsigned long long*)dst = v.lo; *(unsigned long long*)(dst + 4) = v.hi;
}

// ---------------- GEMM core (A system-coherent, B cached weights) ----------
// A: row-major [64][lda] bf16 via sc0sc1 u64 loads (depth-2 reg prefetch).
// B: row-major B^T [64][ldb] bf16, plain cached (L2-hot weights).
// 256 threads, 4 waves 2x2, wave tile 32x32 (2x2 16x16x32 frags). LDS dbuf.
template<int NK>
DI void gemm_sys(const unsigned short* Ab, int lda,
                 const unsigned short* Bb, int ldb,
                 short* sA, short* sB, f32x4 acc[2][2])
{
  const int tid  = threadIdx.x;
  const int lane = tid & 63;
  const int w = tid >> 6, wm = w >> 1, wn = w & 1;
  const unsigned short* ga = Ab + (tid >> 2) * lda + (tid & 3) * 8;
  const unsigned short* gb = Bb + (tid >> 2) * ldb + (tid & 3) * 8;
  const int arow0 = (wm * 32 + (lane & 15)) * 32 + (lane >> 4) * 8;
  const int brow0 = (wn * 32 + (lane & 15)) * 32 + (lane >> 4) * 8;

  a16x8 a0 = ldA(ga), a1 = {};
  s16x8 b0 = *(const s16x8*)gb, b1 = {};
  if (NK > 1) { a1 = ldA(ga + 32); b1 = *(const s16x8*)(gb + 32); }
  stA_lds(&sA[tid * 8], a0);
  *(s16x8*)&sB[tid * 8] = b0;
  __syncthreads();
  #pragma unroll
  for (int k = 0; k < NK; ++k) {
    const int cur = (k & 1) * 2048;
    if (k + 2 < NK) {   // tile j=k+2 goes to reg set of parity j&1 == k&1
      if ((k & 1) == 0) { a0 = ldA(ga + (k + 2) * 32); b0 = *(const s16x8*)(gb + (k + 2) * 32); }
      else              { a1 = ldA(ga + (k + 2) * 32); b1 = *(const s16x8*)(gb + (k + 2) * 32); }
    }
    s16x8 A0 = *(const s16x8*)&sA[cur + arow0];
    s16x8 A1 = *(const s16x8*)&sA[cur + arow0 + 16 * 32];
    s16x8 B0 = *(const s16x8*)&sB[cur + brow0];
    s16x8 B1 = *(const s16x8*)&sB[cur + brow0 + 16 * 32];
    acc[0][0] = __builtin_amdgcn_mfma_f32_16x16x32_bf16(asbf(A0), asbf(B0), acc[0][0], 0, 0, 0);
    acc[0][1] = __builtin_amdgcn_mfma_f32_16x16x32_bf16(asbf(A0), asbf(B1), acc[0][1], 0, 0, 0);
    acc[1][0] = __builtin_amdgcn_mfma_f32_16x16x32_bf16(asbf(A1), asbf(B0), acc[1][0], 0, 0, 0);
    acc[1][1] = __builtin_amdgcn_mfma_f32_16x16x32_bf16(asbf(A1), asbf(B1), acc[1][1], 0, 0, 0);
    if (k + 1 < NK) {   // tile j=k+1 lives in reg set parity (k+1)&1
      const int nxt = ((k + 1) & 1) * 2048;
      if ((k & 1) == 0) { stA_lds(&sA[nxt + tid * 8], a1); *(s16x8*)&sB[nxt + tid * 8] = b1; }
      else              { stA_lds(&sA[nxt + tid * 8], a0); *(s16x8*)&sB[nxt + tid * 8] = b0; }
    }
    __syncthreads();
  }
}

// Variant: A is fp32 (normal cached), K real = KREAL. Used by k_proj only.
template<int NK, int KREAL>
DI void gemm_f32A(const float* Af, int lda,
                  const unsigned short* Bb, int ldb,
                  short* sA, short* sB, f32x4 acc[2][2])
{
  const int tid  = threadIdx.x;
  const int lane = tid & 63;
  const int w = tid >> 6, wm = w >> 1, wn = w & 1;
  const float* ga = Af + (tid >> 2) * lda;
  const int cseg  = (tid & 3) * 8;
  const unsigned short* gb = Bb + (tid >> 2) * ldb + (tid & 3) * 8;
  const int arow0 = (wm * 32 + (lane & 15)) * 32 + (lane >> 4) * 8;
  const int brow0 = (wn * 32 + (lane & 15)) * 32 + (lane >> 4) * 8;

  auto loadA = [&](int k) -> s16x8 {
    s16x8 r;
    const int c0 = k * 32 + cseg;
    if (c0 + 8 <= KREAL) {
      float4 f0 = *(const float4*)(ga + c0);
      float4 f1 = *(const float4*)(ga + c0 + 4);
      r[0] = (short)f2bf(f0.x); r[1] = (short)f2bf(f0.y);
      r[2] = (short)f2bf(f0.z); r[3] = (short)f2bf(f0.w);
      r[4] = (short)f2bf(f1.x); r[5] = (short)f2bf(f1.y);
      r[6] = (short)f2bf(f1.z); r[7] = (short)f2bf(f1.w);
    } else {
      #pragma unroll
      for (int j = 0; j < 8; ++j) {
        float x = (c0 + j < KREAL) ? ga[c0 + j] : 0.0f;
        r[j] = (short)f2bf(x);
      }
    }
    return r;
  };

  s16x8 va = loadA(0);
  s16x8 vb = *(const s16x8*)gb;
  *(s16x8*)&sA[tid * 8] = va;
  *(s16x8*)&sB[tid * 8] = vb;
  __syncthreads();
  for (int k = 0; k < NK; ++k) {
    const int cur = (k & 1) * 2048;
    if (k + 1 < NK) {
      va = loadA(k + 1);
      vb = *(const s16x8*)(gb + (k + 1) * 32);
    }
    s16x8 a0 = *(const s16x8*)&sA[cur + arow0];
    s16x8 a1 = *(const s16x8*)&sA[cur + arow0 + 16 * 32];
    s16x8 b0 = *(const s16x8*)&sB[cur + brow0];
    s16x8 b1 = *(const s16x8*)&sB[cur + brow0 + 16 * 32];
    acc[0][0] = __builtin_amdgcn_mfma_f32_16x16x32_bf16(asbf(a0), asbf(b0), acc[0][0], 0, 0, 0);
    acc[0][1] = __builtin_amdgcn_mfma_f32_16x16x32_bf16(asbf(a0), asbf(b1), acc[0][1], 0, 0, 0);
    acc[1][0] = __builtin_amdgcn_mfma_f32_16x16x32_bf16(asbf(a1), asbf(b0), acc[1][0], 0, 0, 0);
    acc[1][1] = __builtin_amdgcn_mfma_f32_16x16x32_bf16(asbf(a1), asbf(b1), acc[1][1], 0, 0, 0);
    if (k + 1 < NK) {
      const int nxt = ((k + 1) & 1) * 2048;
      *(s16x8*)&sA[nxt + tid * 8] = va;
      *(s16x8*)&sB[nxt + tid * 8] = vb;
    }
    __syncthreads();
  }
}

// epilogue iterator: f(rowl, coll, acc_value) for the 64x64 block tile
template<typename F>
DI void epiloop(f32x4 acc[2][2], F&& f) {
  const int lane = threadIdx.x & 63;
  const int w = threadIdx.x >> 6, wm = w >> 1, wn = w & 1;
  #pragma unroll
  for (int mi = 0; mi < 2; ++mi)
    #pragma unroll
    for (int ni = 0; ni < 2; ++ni)
      #pragma unroll
      for (int r = 0; r < 4; ++r) {
        const int rowl = wm * 32 + mi * 16 + (lane >> 4) * 4 + r;
        const int coll = wn * 32 + ni * 16 + (lane & 15);
        f(rowl, coll, acc[mi][ni][r]);
      }
}

// pack-store a 64x64 u16 LDS tile to system memory as u64s (16 per row)
DI void pack_store_tile(const unsigned short* lds16, unsigned short* dstbase, int ldd) {
  const unsigned long long* l64 = (const unsigned long long*)lds16;
  #pragma unroll
  for (int it = 0; it < 4; ++it) {
    const int i = it * 256 + threadIdx.x;
    const int row = i >> 4, q = i & 15;
    st_sys_u64(dstbase + row * ldd + q * 4, l64[row * 16 + q]);
  }
}

// ---------------- prep kernels ----------------
__global__ void k_prep_wpt(const float* __restrict__ Wi, unsigned short* __restrict__ WpT) {
  int i = blockIdx.x * 256 + threadIdx.x;
  if (i >= 320 * 320) return;
  int n = i / 320, k = i % 320;
  float v = (n < 300 && k < 300) ? Wi[k * 300 + n] : 0.0f;
  WpT[i] = f2bf(v);
}
__global__ void k_prep_qpt(const float* __restrict__ Q, unsigned short* __restrict__ QpT) {
  int i = blockIdx.x * 256 + threadIdx.x;
  if (i >= 320 * 512) return;
  int n = i >> 9, k = i & 511;
  float v = (n < 300) ? Q[k * 300 + n] : 0.0f;
  QpT[i] = f2bf(v);
}
__global__ void k_prep_rpt(const float* __restrict__ R, unsigned short* __restrict__ RpT) {
  int i = blockIdx.x * 256 + threadIdx.x;
  if (i >= 512 * 320) return;
  int n = i / 320, k = i % 320;
  float v = (k < 300) ? R[k * 512 + n] : 0.0f;
  RpT[i] = f2bf(v);
}
__global__ void k_prep_wgt(const float* __restrict__ Wih, const float* __restrict__ Whh,
                           unsigned short* __restrict__ WgT) {
  int i = blockIdx.x * 256 + threadIdx.x;
  if (i >= 2048 * 832) return;
  int np = i / 832, k = i % 832;
  int c = np >> 2, g = np & 3, col = g * 512 + c;
  float v = 0.0f;
  if (k < 300) v = Wih[k * 2048 + col];
  else if (k >= 320) v = Whh[(k - 320) * 2048 + col];
  WgT[i] = f2bf(v);
}
__global__ void k_prep_bg(const float* __restrict__ bih, const float* __restrict__ bhh,
                          float* __restrict__ bg) {
  int i = blockIdx.x * 256 + threadIdx.x;
  if (i >= 2048) return;
  int c = i >> 2, g = i & 3, col = g * 512 + c;
  bg[i] = bih[col] + bhh[col];
}
__global__ void k_prep_vt(const float* __restrict__ Wc3, const float* __restrict__ Wc4,
                          const float* __restrict__ Wc5, unsigned short* __restrict__ VT) {
  int i = blockIdx.x * 256 + threadIdx.x;
  if (i >= 64 * 512) return;
  int j = i >> 9, k = i & 511;
  float v = 0.0f;
  if (j < 9)       { int f = j / 3,  dt = j % 3;        v = Wc3[(f * 3 + dt) * 512 + k]; }
  else if (j < 21) { int jj = j - 9;  int f = jj / 4, dt = jj % 4; v = Wc4[(f * 4 + dt) * 512 + k]; }
  else if (j < 36) { int jj = j - 21; int f = jj / 5, dt = jj % 5; v = Wc5[(f * 5 + dt) * 512 + k]; }
  VT[i] = f2bf(v);
}
__global__ void k_wsfail(float* out, int n, float v) {
  int i = blockIdx.x * 256 + threadIdx.x;
  if (i < n) out[i] = -v;
}

// ---------------- input projection ----------------
__global__ __launch_bounds__(256) void k_proj(const float* __restrict__ x,
                                              const unsigned short* __restrict__ WpT,
                                              const float* __restrict__ b_in,
                                              unsigned short* __restrict__ xin) {
  __shared__ short sA[4096], sB[4096];
  const int m0 = blockIdx.x * 64, n0 = blockIdx.y * 64;
  f32x4 acc[2][2];
  const f32x4 z = {0.f, 0.f, 0.f, 0.f};
  acc[0][0] = z; acc[0][1] = z; acc[1][0] = z; acc[1][1] = z;
  gemm_f32A<10, 300>(x + (size_t)m0 * 300, 300, WpT + n0 * 320, 320, sA, sB, acc);
  epiloop(acc, [&](int rowl, int coll, float vacc) {
    const int row = m0 + rowl, col = n0 + coll;
    float o = 0.0f;
    if (col < 300) o = tanh_(vacc + b_in[col]);
    const int b = row >> 8, s = row & 255;
    xin[(size_t)(s * 512 + b) * KP_ + col] = f2bf(o);
  });
}

// ---------------- persistent scan kernel ----------------
// 256 WGs x 256 threads in 8 INDEPENDENT groups of 32 WGs; group g owns batch
// rows 64g..64g+63 for all phases (recurrence is batch-row-local; only weights
// are shared and they are read-only L2-cached). Cross-WG data (act, hs, hfp)
// moves only through sc0sc1 (LLC-coherent) loads/stores -> no cache fences.
// Barrier: single relaxed atomic counter per group, 32 arrivals, + vmcnt(0).
__global__ __launch_bounds__(256) void k_scan(
    const unsigned short* __restrict__ xin,
    const unsigned short* __restrict__ QpT,
    const unsigned short* __restrict__ RpT,
    const unsigned short* __restrict__ WgT,
    const float* __restrict__ bg,
    const unsigned short* __restrict__ VT,
    unsigned short* __restrict__ hs,
    unsigned short* __restrict__ act,
    float* __restrict__ hfp,
    float* __restrict__ U,
    unsigned int* __restrict__ bar)
{
  __shared__ short sA[4096], sB[4096];
  __shared__ float gbuf[4096];
  const int wg  = blockIdx.x;
  const int grp = wg >> 5;        // batch-row group: rows 64*grp .. 64*grp+63
  const int l   = wg & 31;        // lane-in-group
  const int tid = threadIdx.x;
  const f32x4 z = {0.f, 0.f, 0.f, 0.f};

  // gates tile assignment (static across steps -> cell state in registers)
  const int gm0 = grp * 64;             // batch-row tile
  const int gn0 = l * 64;               // gate-col tile (permuted n' = 4c+g)
  float c_state[4] = {0.f, 0.f, 0.f, 0.f};

  int ep = 0;  // barrier epoch
  auto bar_sync = [&]() {
    wait_vm<0>();        // each wave drains its own system-stores to LLC
    __syncthreads();
    if (tid == 0) {
      __hip_atomic_fetch_add(&bar[grp * 64], 1u,
                             __ATOMIC_RELAXED, __HIP_MEMORY_SCOPE_AGENT);
      const unsigned tgt = (unsigned)(ep + 1) * 32u;
      while (__hip_atomic_load(&bar[grp * 64], __ATOMIC_RELAXED,
                               __HIP_MEMORY_SCOPE_AGENT) < tgt)
        __builtin_amdgcn_s_sleep(1);
    }
    __syncthreads();
    ++ep;
  };

  for (int t = 0; t < S_; ++t) {
    const unsigned short* hst = hs + (size_t)(t % NRING) * HSLOT;
    unsigned short*       hso = hs + (size_t)((t + 1) % NRING) * HSLOT;

    // ---- P1: act[g rows, 0:320] = 2*sigm(h_{t-1} @ Q) * xin_t  (5 tiles)
    if (l < 5) {
      const int m0 = gm0, n0 = l * 64;
      f32x4 acc[2][2];
      acc[0][0] = z; acc[0][1] = z; acc[1][0] = z; acc[1][1] = z;
      gemm_sys<16>(hst + m0 * 512, 512, QpT + n0 * 512, 512, sA, sB, acc);
      const unsigned short* xin_t = xin + (size_t)t * 512 * KP_;
      unsigned short* g16 = (unsigned short*)gbuf;
      epiloop(acc, [&](int rowl, int coll, float vacc) {
        const int row = m0 + rowl, col = n0 + coll;
        g16[rowl * 64 + coll] = f2bf(2.0f * sigm(vacc) * bf2f(xin_t[row * KP_ + col]));
      });
      __syncthreads();
      pack_store_tile(g16, act + m0 * ALD_ + n0, ALD_);
    }
    bar_sync();

    // ---- P2: act[g rows, 320:832] = 2*sigm(xt @ R) * hfp  (8 tiles)
    if (l < 8) {
      const int m0 = gm0, n0 = l * 64;
      // cooperative hfp tile load into gbuf (latency hides under the GEMM)
      unsigned long long* g64 = (unsigned long long*)gbuf;
      #pragma unroll
      for (int it = 0; it < 8; ++it) {
        const int i = it * 256 + tid;
        const int row = i >> 5, p = i & 31;
        g64[row * 32 + p] = ld_sys_u64(hfp + (m0 + row) * 512 + n0 + p * 2);
      }
      f32x4 acc[2][2];
      acc[0][0] = z; acc[0][1] = z; acc[1][0] = z; acc[1][1] = z;
      gemm_sys<10>(act + m0 * ALD_, ALD_, RpT + n0 * KP_, KP_, sA, sB, acc);
      unsigned short* g16 = (unsigned short*)sA;   // sA free after gemm
      epiloop(acc, [&](int rowl, int coll, float vacc) {
        g16[rowl * 64 + coll] = f2bf(2.0f * sigm(vacc) * gbuf[rowl * 64 + coll]);
      });
      __syncthreads();
      pack_store_tile(g16, act + m0 * ALD_ + 320 + n0, ALD_);
    }
    bar_sync();

    // ---- P3: gates GEMM + cell update (32 tiles, Ct in registers)
    {
      f32x4 acc[2][2];
      acc[0][0] = z; acc[0][1] = z; acc[1][0] = z; acc[1][1] = z;
      gemm_sys<26>(act + gm0 * ALD_, ALD_, WgT + gn0 * 832, 832, sA, sB, acc);
      epiloop(acc, [&](int rowl, int coll, float vacc) {
        gbuf[rowl * 64 + coll] = vacc;
      });
      unsigned short* hbuf = (unsigned short*)sA;  // 64x16 u16 (free after gemm)
      float*          fbuf = (float*)sB;           // 64x16 f32
      __syncthreads();
      #pragma unroll
      for (int q = 0; q < 4; ++q) {
        const int item = q * 256 + tid;
        const int row = item >> 4, cu = item & 15;
        const float4 bb = *(const float4*)&bg[gn0 + cu * 4];
        const float iv = gbuf[row * 64 + cu * 4 + 0] + bb.x;
        const float fv = gbuf[row * 64 + cu * 4 + 1] + bb.y;
        const float gv = gbuf[row * 64 + cu * 4 + 2] + bb.z;
        const float ov = gbuf[row * 64 + cu * 4 + 3] + bb.w;
        const float cn = sigm(fv) * c_state[q] + sigm(iv) * tanh_(gv);
        const float h  = sigm(ov) * tanh_(cn);
        c_state[q] = cn;
        hbuf[row * 16 + cu] = f2bf(h);
        fbuf[row * 16 + cu] = h;
      }
      __syncthreads();
      // pack-store h (64x16 u16 = 256 u64) and hfp (64x16 f32 = 512 u64)
      {
        const unsigned long long* h64 = (const unsigned long long*)hbuf;
        const int row = tid >> 2, q = tid & 3;
        st_sys_u64(hso + (gm0 + row) * 512 + (gn0 >> 2) + q * 4, h64[row * 4 + q]);
        const unsigned long long* f64 = (const unsigned long long*)fbuf;
        #pragma unroll
        for (int it = 0; it < 2; ++it) {
          const int i = it * 256 + tid;
          const int r2 = i >> 3, p = i & 7;
          st_sys_u64(hfp + (gm0 + r2) * 512 + (gn0 >> 2) + p * 2, f64[r2 * 8 + p]);
        }
      }
      __syncthreads();
    }
    bar_sync();

    // ---- convU every 32 steps: group handles its own 64 rows x 32 timesteps
    if ((t & 31) == 31) {
      const int c = t >> 5;
      const int tglob = 32 * c + l;
      const int slot = (tglob + 1) % NRING;
      const int brow = gm0;
      f32x4 acc[2][2];
      acc[0][0] = z; acc[0][1] = z; acc[1][0] = z; acc[1][1] = z;
      gemm_sys<16>(hs + (size_t)slot * HSLOT + (size_t)brow * 512, 512, VT, 512, sA, sB, acc);
      epiloop(acc, [&](int rowl, int coll, float vacc) {
        U[((size_t)(brow + rowl) * 256 + tglob) * 64 + coll] = vacc;
      });
    }
  }
}

// window-sum + relu + global max pool + final linear
__global__ __launch_bounds__(256) void k_combine(const float* __restrict__ U,
                                                 const float* __restrict__ bc3,
                                                 const float* __restrict__ bc4,
                                                 const float* __restrict__ bc5,
                                                 const float* __restrict__ Wl,
                                                 const float* __restrict__ bl,
                                                 float* __restrict__ out) {
  const int b = blockIdx.x;
  const int p = threadIdx.x;
  const float* Ub = U + (size_t)b * (256 * 64);
  float v[9];
  #pragma unroll
  for (int j = 0; j < 9; ++j) v[j] = -1e30f;
  if (p < 254) {
    #pragma unroll
    for (int f = 0; f < 3; ++f)
      v[f] = Ub[(p + 0) * 64 + f * 3 + 0] + Ub[(p + 1) * 64 + f * 3 + 1] + Ub[(p + 2) * 64 + f * 3 + 2];
  }
  if (p < 253) {
    #pragma unroll
    for (int f = 0; f < 3; ++f)
      v[3 + f] = Ub[(p + 0) * 64 + 9 + f * 4 + 0] + Ub[(p + 1) * 64 + 9 + f * 4 + 1] +
                 Ub[(p + 2) * 64 + 9 + f * 4 + 2] + Ub[(p + 3) * 64 + 9 + f * 4 + 3];
  }
  if (p < 252) {
    #pragma unroll
    for (int f = 0; f < 3; ++f)
      v[6 + f] = Ub[(p + 0) * 64 + 21 + f * 5 + 0] + Ub[(p + 1) * 64 + 21 + f * 5 + 1] +
                 Ub[(p + 2) * 64 + 21 + f * 5 + 2] + Ub[(p + 3) * 64 + 21 + f * 5 + 3] +
                 Ub[(p + 4) * 64 + 21 + f * 5 + 4];
  }
  __shared__ float red[4][9];
  const int lane = threadIdx.x & 63, w = threadIdx.x >> 6;
  #pragma unroll
  for (int j = 0; j < 9; ++j) {
    float m = v[j];
    #pragma unroll
    for (int off = 32; off >= 1; off >>= 1) m = fmaxf(m, __shfl_xor(m, off));
    if (lane == 0) red[w][j] = m;
  }
  __syncthreads();
  if (threadIdx.x < 2) {
    const int k = threadIdx.x;
    float o = bl[k];
    #pragma unroll
    for (int j = 0; j < 9; ++j) {
      float m = fmaxf(fmaxf(red[0][j], red[1][j]), fmaxf(red[2][j], red[3][j]));
      float bias = (j < 3) ? bc3[j] : (j < 6) ? bc4[j - 3] : bc5[j - 6];
      o += fmaxf(m + bias, 0.0f) * Wl[j * 2 + k];
    }
    out[b * 2 + k] = o;
  }
}

// ---------------- host launch ----------------
extern "C" void kernel_launch(void* const* d_in, const int* in_sizes, int n_in,
                              void* d_out, int out_size, void* d_ws, size_t ws_size,
                              hipStream_t stream) {
  const float* x     = (const float*)d_in[0];
  const float* W_in  = (const float*)d_in[1];
  const float* b_in  = (const float*)d_in[2];
  const float* Wih   = (const float*)d_in[3];
  const float* Whh   = (const float*)d_in[4];
  const float* bih   = (const float*)d_in[5];
  const float* bhh   = (const float*)d_in[6];
  const float* Q     = (const float*)d_in[7];
  const float* R     = (const float*)d_in[8];
  const float* Wc3   = (const float*)d_in[9];
  const float* bc3   = (const float*)d_in[10];
  const float* Wc4   = (const float*)d_in[11];
  const float* bc4   = (const float*)d_in[12];
  const float* Wc5   = (const float*)d_in[13];
  const float* bc5   = (const float*)d_in[14];
  const float* W_lin = (const float*)d_in[15];
  const float* b_lin = (const float*)d_in[16];

  if (ws_size < WS_NEED) {  // diagnosable marker: absmax ≈ ws_size in MB
    k_wsfail<<<4, 256, 0, stream>>>((float*)d_out, out_size, (float)(ws_size >> 20));
    return;
  }

  char* ws = (char*)d_ws;
  unsigned short* xin = (unsigned short*)(ws + OFF_XIN);
  float*          U   = (float*)(ws + OFF_U);
  unsigned short* hs  = (unsigned short*)(ws + OFF_HS);
  unsigned short* act = (unsigned short*)(ws + OFF_ACT);
  float*          hfp = (float*)(ws + OFF_HFP);
  unsigned short* WpT = (unsigned short*)(ws + OFF_WPT);
  unsigned short* QpT = (unsigned short*)(ws + OFF_QPT);
  unsigned short* RpT = (unsigned short*)(ws + OFF_RPT);
  unsigned short* WgT = (unsigned short*)(ws + OFF_WGT);
  float*          bg  = (float*)(ws + OFF_BG);
  unsigned short* VT  = (unsigned short*)(ws + OFF_VT);
  unsigned int*   bar = (unsigned int*)(ws + OFF_BAR);

  // per-replay init: h0 = c0 = 0 (ring slot 0 + hfp), barrier counters = 0
  (void)hipMemsetAsync(hs, 0, HSLOT * 2, stream);
  (void)hipMemsetAsync(hfp, 0, SZ_HFP, stream);
  (void)hipMemsetAsync(bar, 0, SZ_BAR, stream);

  // weight prep
  k_prep_wpt<<<(320 * 320 + 255) / 256, 256, 0, stream>>>(W_in, WpT);
  k_prep_qpt<<<(320 * 512 + 255) / 256, 256, 0, stream>>>(Q, QpT);
  k_prep_rpt<<<(512 * 320 + 255) / 256, 256, 0, stream>>>(R, RpT);
  k_prep_wgt<<<(2048 * 832 + 255) / 256, 256, 0, stream>>>(Wih, Whh, WgT);
  k_prep_bg<<<8, 256, 0, stream>>>(bih, bhh, bg);
  k_prep_vt<<<(64 * 512 + 255) / 256, 256, 0, stream>>>(Wc3, Wc4, Wc5, VT);

  // input projection
  k_proj<<<dim3(131072 / 64, KP_ / 64), 256, 0, stream>>>(x, WpT, b_in, xin);

  // persistent scan (entire 256-step recurrence in one dispatch)
  k_scan<<<NWG, 256, 0, stream>>>(xin, QpT, RpT, WgT, bg, VT, hs, act, hfp, U, bar);

  // conv window-max + final linear
  k_combine<<<512, 256, 0, stream>>>(U, bc3, bc4, bc5, W_lin, b_lin, (float*)d_out);
}